// Round 1
// baseline (136.886 us; speedup 1.0000x reference)
//
#include <hip/hip_runtime.h>
#include <hip/hip_bf16.h>
#include <hip/hip_cooperative_groups.h>

// Problem: B=4, S=4096, D=64, fp32 in/out.
// out[b,i,d] = sum_j (q[b,i,:]·k[b,j,:]) * v[b,j,d]  ==  Q @ (K^T @ V)  (no softmax)
// Factored: M[b] = K^T V (64x64 per batch), out = Q @ M. 268 MFLOP, ~16MiB traffic.
//
// Fused single cooperative kernel:
//   phase A: per-block 64-row chunk partial M  -> ws
//   grid sync
//   phase B: 256-block parallel reduce -> MB (bf16, MFMA B-frag order)
//   grid sync
//   phase C: out = Q @ M via mfma_f32_16x16x32_bf16 (Q frags prefetched at top)

#define BATCH 4
#define SEQ   4096
#define DIM   64
#define NCH   64      // chunks per batch
#define CHUNK 64      // rows per chunk

namespace cg = cooperative_groups;

typedef float f4  __attribute__((ext_vector_type(4)));
typedef short bf16x8 __attribute__((ext_vector_type(8)));
typedef float f32x4  __attribute__((ext_vector_type(4)));

__device__ inline unsigned short f2bf(float f) {
    union { float f; unsigned u; } v; v.f = f;
    unsigned r = (v.u + 0x7fffu + ((v.u >> 16) & 1u)) >> 16;  // RTN-even
    return (unsigned short)r;
}

__global__ __launch_bounds__(256) void fused_attn(const float* __restrict__ Q,
                                                  const float* __restrict__ K,
                                                  const float* __restrict__ V,
                                                  float* __restrict__ out,
                                                  float* __restrict__ part,
                                                  unsigned short* __restrict__ MB) {
    __shared__ f4 Ks[1024];   // 64 rows x 16 float4
    __shared__ f4 Vs[1024];
    const int bx = blockIdx.x;        // b*64 + chunk
    const int t  = threadIdx.x;

    // ---------- Prefetch Q fragments (consumed in phase C; latency hides under A) ----
    const int wave = t >> 6, lane = t & 63;
    const int m = lane & 15, quad = lane >> 4;
    const int b = bx >> 6;
    const int row0 = (bx & 63) * 64 + wave * 16;
    const float* qrow = Q + ((size_t)b * SEQ + row0 + m) * DIM;
    const f4* qp0 = (const f4*)(qrow + quad * 8);         // ks=0: cols quad*8 .. +8
    const f4* qp1 = (const f4*)(qrow + 32 + quad * 8);    // ks=1
    f4 q0a = qp0[0], q0b = qp0[1];
    f4 q1a = qp1[0], q1b = qp1[1];

    // ---------- Phase A: partial M = K_chunk^T @ V_chunk -------------------------
    {
        const f4* Kg = (const f4*)(K + (size_t)bx * (CHUNK * DIM));
        const f4* Vg = (const f4*)(V + (size_t)bx * (CHUNK * DIM));
#pragma unroll
        for (int i = 0; i < 4; ++i) {
            Ks[t + 256 * i] = Kg[t + 256 * i];
            Vs[t + 256 * i] = Vg[t + 256 * i];
        }
        __syncthreads();
        const int rg = t >> 4;     // rows r0 = rg*4 (d1)
        const int cgi = t & 15;    // cols c0 = cgi*4 (d2)
        f4 a0 = 0.f, a1 = 0.f, a2 = 0.f, a3 = 0.f;
#pragma unroll 8
        for (int j = 0; j < CHUNK; ++j) {
            f4 a = Ks[j * 16 + rg];
            f4 v = Vs[j * 16 + cgi];
            a0 += v * a.x;
            a1 += v * a.y;
            a2 += v * a.z;
            a3 += v * a.w;
        }
        f4* P = (f4*)part + (size_t)bx * 1024;   // 64x64 partial, row-major
        P[(rg * 4 + 0) * 16 + cgi] = a0;
        P[(rg * 4 + 1) * 16 + cgi] = a1;
        P[(rg * 4 + 2) * 16 + cgi] = a2;
        P[(rg * 4 + 3) * 16 + cgi] = a3;
    }

    cg::this_grid().sync();

    // ---------- Phase B: reduce 64 partials -> MB (bf16, B-frag order) -----------
    // 65536 threads, 4 threads per M element; partials are L2/LLC-hot.
    {
        const int g   = bx * 256 + t;
        const int e   = g >> 2;          // 0..16383  (b*4096 + d'*64 + c)
        const int sub = g & 3;           // 16 partials each
        const int eb  = e >> 12;
        const int idx = e & 4095;
        const float* pp = part + ((size_t)(eb * NCH + sub * 16)) * 4096 + idx;
        float s = 0.f;
#pragma unroll
        for (int p = 0; p < 16; ++p) s += pp[(size_t)p * 4096];
        s += __shfl_xor(s, 1);
        s += __shfl_xor(s, 2);
        if (sub == 0) {
            const int dp = idx >> 6;      // k index (d')
            const int c  = idx & 63;      // n index
            const int ct = c >> 4, mm = c & 15;
            const int ks = dp >> 5, qd = (dp >> 3) & 3, j = dp & 7;
            MB[(((eb * 8 + ct * 2 + ks) * 64) + qd * 16 + mm) * 8 + j] = f2bf(s);
        }
    }

    cg::this_grid().sync();

    // ---------- Phase C: out = Q @ M via MFMA ------------------------------------
    {
        bf16x8 afrag[2];
        {
            bf16x8 a;
            a[0] = (short)f2bf(q0a.x); a[1] = (short)f2bf(q0a.y);
            a[2] = (short)f2bf(q0a.z); a[3] = (short)f2bf(q0a.w);
            a[4] = (short)f2bf(q0b.x); a[5] = (short)f2bf(q0b.y);
            a[6] = (short)f2bf(q0b.z); a[7] = (short)f2bf(q0b.w);
            afrag[0] = a;
            a[0] = (short)f2bf(q1a.x); a[1] = (short)f2bf(q1a.y);
            a[2] = (short)f2bf(q1a.z); a[3] = (short)f2bf(q1a.w);
            a[4] = (short)f2bf(q1b.x); a[5] = (short)f2bf(q1b.y);
            a[6] = (short)f2bf(q1b.z); a[7] = (short)f2bf(q1b.w);
            afrag[1] = a;
        }

        const bf16x8* MBv = (const bf16x8*)MB + (size_t)b * 8 * 64;
        f32x4 acc[4];
#pragma unroll
        for (int ct = 0; ct < 4; ++ct) acc[ct] = (f32x4)0.f;
#pragma unroll
        for (int ct = 0; ct < 4; ++ct) {
#pragma unroll
            for (int ks = 0; ks < 2; ++ks) {
                bf16x8 bfrag = MBv[(ct * 2 + ks) * 64 + lane];
                acc[ct] = __builtin_amdgcn_mfma_f32_16x16x32_bf16(afrag[ks], bfrag, acc[ct], 0, 0, 0);
            }
        }

        // C/D layout: col = ct*16 + (lane&15), row = quad*4 + reg
        float* orow = out + ((size_t)b * SEQ + row0) * DIM;
#pragma unroll
        for (int ct = 0; ct < 4; ++ct) {
#pragma unroll
            for (int r = 0; r < 4; ++r) {
                orow[(quad * 4 + r) * DIM + ct * 16 + m] = acc[ct][r];
            }
        }
    }
}

// ------------- Fallback path (if cooperative launch is rejected under capture) ---
__global__ __launch_bounds__(256) void k1_partial(const float* __restrict__ K,
                                                  const float* __restrict__ V,
                                                  float* __restrict__ part) {
    __shared__ f4 Ks[1024];
    __shared__ f4 Vs[1024];
    const int bx = blockIdx.x;
    const int t  = threadIdx.x;
    const f4* Kg = (const f4*)(K + (size_t)bx * (CHUNK * DIM));
    const f4* Vg = (const f4*)(V + (size_t)bx * (CHUNK * DIM));
#pragma unroll
    for (int i = 0; i < 4; ++i) {
        Ks[t + 256 * i] = Kg[t + 256 * i];
        Vs[t + 256 * i] = Vg[t + 256 * i];
    }
    __syncthreads();
    const int rg = t >> 4, cgi = t & 15;
    f4 a0 = 0.f, a1 = 0.f, a2 = 0.f, a3 = 0.f;
#pragma unroll 8
    for (int j = 0; j < CHUNK; ++j) {
        f4 a = Ks[j * 16 + rg];
        f4 v = Vs[j * 16 + cgi];
        a0 += v * a.x; a1 += v * a.y; a2 += v * a.z; a3 += v * a.w;
    }
    f4* P = (f4*)part + (size_t)bx * 1024;
    P[(rg * 4 + 0) * 16 + cgi] = a0;
    P[(rg * 4 + 1) * 16 + cgi] = a1;
    P[(rg * 4 + 2) * 16 + cgi] = a2;
    P[(rg * 4 + 3) * 16 + cgi] = a3;
}

__global__ __launch_bounds__(256) void k2_reduce(const float* __restrict__ part,
                                                 unsigned short* __restrict__ MB) {
    const int tg = blockIdx.x * 256 + threadIdx.x;
    const int b = tg >> 12;
    const int e = tg & 4095;
    float s = 0.f;
#pragma unroll 8
    for (int p = 0; p < NCH; ++p)
        s += part[((size_t)(b * NCH + p)) * 4096 + e];
    const int dp = e >> 6;
    const int c  = e & 63;
    const int ct = c >> 4, mm = c & 15;
    const int ks = dp >> 5, qd = (dp >> 3) & 3, j = dp & 7;
    MB[(((b * 8 + ct * 2 + ks) * 64) + qd * 16 + mm) * 8 + j] = f2bf(s);
}

__global__ __launch_bounds__(256) void k3_qm(const float* __restrict__ Q,
                                             const unsigned short* __restrict__ MB,
                                             float* __restrict__ out) {
    const int bx = blockIdx.x;
    const int t  = threadIdx.x;
    const int wave = t >> 6, lane = t & 63;
    const int m = lane & 15, quad = lane >> 4;
    const int b = bx >> 6;
    const int row0 = (bx & 63) * 64 + wave * 16;

    const float* qrow = Q + ((size_t)b * SEQ + row0 + m) * DIM;
    bf16x8 afrag[2];
#pragma unroll
    for (int ks = 0; ks < 2; ++ks) {
        const f4* qp = (const f4*)(qrow + ks * 32 + quad * 8);
        f4 q1 = qp[0], q2 = qp[1];
        bf16x8 a;
        a[0] = (short)f2bf(q1.x); a[1] = (short)f2bf(q1.y);
        a[2] = (short)f2bf(q1.z); a[3] = (short)f2bf(q1.w);
        a[4] = (short)f2bf(q2.x); a[5] = (short)f2bf(q2.y);
        a[6] = (short)f2bf(q2.z); a[7] = (short)f2bf(q2.w);
        afrag[ks] = a;
    }

    const bf16x8* MBv = (const bf16x8*)MB + (size_t)b * 8 * 64;
    f32x4 acc[4];
#pragma unroll
    for (int ct = 0; ct < 4; ++ct) acc[ct] = (f32x4)0.f;
#pragma unroll
    for (int ct = 0; ct < 4; ++ct) {
#pragma unroll
        for (int ks = 0; ks < 2; ++ks) {
            bf16x8 bfrag = MBv[(ct * 2 + ks) * 64 + lane];
            acc[ct] = __builtin_amdgcn_mfma_f32_16x16x32_bf16(afrag[ks], bfrag, acc[ct], 0, 0, 0);
        }
    }

    float* orow = out + ((size_t)b * SEQ + row0) * DIM;
#pragma unroll
    for (int ct = 0; ct < 4; ++ct) {
#pragma unroll
        for (int r = 0; r < 4; ++r) {
            orow[(quad * 4 + r) * DIM + ct * 16 + m] = acc[ct][r];
        }
    }
}

extern "C" void kernel_launch(void* const* d_in, const int* in_sizes, int n_in,
                              void* d_out, int out_size, void* d_ws, size_t ws_size,
                              hipStream_t stream) {
    const float* q = (const float*)d_in[0];
    const float* k = (const float*)d_in[1];
    const float* v = (const float*)d_in[2];
    float* out = (float*)d_out;

    float* part = (float*)d_ws;                                                      // 4 MiB
    unsigned short* MB = (unsigned short*)((char*)d_ws + (size_t)4 * 1024 * 1024);   // 32 KiB

    void* args[] = { (void*)&q, (void*)&k, (void*)&v, (void*)&out, (void*)&part, (void*)&MB };
    hipError_t err = hipLaunchCooperativeKernel((const void*)&fused_attn,
                                                dim3(BATCH * NCH), dim3(256),
                                                args, 0, stream);
    if (err != hipSuccess) {
        // cooperative launch rejected (e.g. under capture on older ROCm) -> 3-kernel path
        k1_partial<<<BATCH * NCH, 256, 0, stream>>>(k, v, part);
        k2_reduce<<<64, 256, 0, stream>>>(part, MB);
        k3_qm<<<BATCH * NCH, 256, 0, stream>>>(q, MB, out);
    }
}

// Round 2
// 72.421 us; speedup vs baseline: 1.8901x; 1.8901x over previous
//
#include <hip/hip_runtime.h>
#include <hip/hip_bf16.h>

// Problem: B=4, S=4096, D=64, fp32 in/out.
// out[b,i,d] = sum_j (q[b,i,:]·k[b,j,:]) * v[b,j,d]  ==  Q @ (K^T @ V)  (no softmax)
// Factored: M[b] = K^T V (64x64 per batch), out = Q @ M. 268 MFLOP, ~16MiB traffic.
//
// 3-kernel structure (cooperative fusion measured WORSE: grid.sync ~28us each).
// Timed-region budget (measured R0/R1): harness fill 42.5us (HBM-write roofline)
// + ~30us fixed reset dispatches + these kernels (~4-6us). k2 widened to 256 blocks.

#define BATCH 4
#define SEQ   4096
#define DIM   64
#define NCH   64      // chunks per batch (k1)
#define CHUNK 64      // rows per chunk

typedef float f4  __attribute__((ext_vector_type(4)));
typedef short bf16x8 __attribute__((ext_vector_type(8)));
typedef float f32x4  __attribute__((ext_vector_type(4)));

__device__ inline unsigned short f2bf(float f) {
    union { float f; unsigned u; } v; v.f = f;
    unsigned r = (v.u + 0x7fffu + ((v.u >> 16) & 1u)) >> 16;  // RTN-even
    return (unsigned short)r;
}

// ---------------- k1: partial M = K_chunk^T @ V_chunk --------------------
// grid 256 = batch*64 + chunk; block 256. LDS 32KB. Each thread: 4x4 tile of 64x64 M.
__global__ __launch_bounds__(256) void k1_partial(const float* __restrict__ K,
                                                  const float* __restrict__ V,
                                                  float* __restrict__ part) {
    __shared__ f4 Ks[1024];   // 64 rows x 16 float4
    __shared__ f4 Vs[1024];
    const int bx = blockIdx.x;        // b*64 + ch
    const int t  = threadIdx.x;
    const f4* Kg = (const f4*)(K + (size_t)bx * (CHUNK * DIM));
    const f4* Vg = (const f4*)(V + (size_t)bx * (CHUNK * DIM));
#pragma unroll
    for (int i = 0; i < 4; ++i) {
        Ks[t + 256 * i] = Kg[t + 256 * i];
        Vs[t + 256 * i] = Vg[t + 256 * i];
    }
    __syncthreads();
    const int rg = t >> 4;     // rows r0 = rg*4 (d1)
    const int cg = t & 15;     // cols c0 = cg*4 (d2)
    f4 acc0 = 0.f, acc1 = 0.f, acc2 = 0.f, acc3 = 0.f;
#pragma unroll 8
    for (int j = 0; j < CHUNK; ++j) {
        f4 a = Ks[j * 16 + rg];   // broadcast within 16-lane group
        f4 v = Vs[j * 16 + cg];   // 256B contiguous per 16-lane group
        acc0 += v * a.x;
        acc1 += v * a.y;
        acc2 += v * a.z;
        acc3 += v * a.w;
    }
    f4* P = (f4*)part + (size_t)bx * 1024;   // 64x64 partial, row-major
    P[(rg * 4 + 0) * 16 + cg] = acc0;
    P[(rg * 4 + 1) * 16 + cg] = acc1;
    P[(rg * 4 + 2) * 16 + cg] = acc2;
    P[(rg * 4 + 3) * 16 + cg] = acc3;
}

// ---------------- k2: reduce partials -> M, emit bf16 in MFMA B-frag order ----
// WIDENED: grid 256 x 256 (full machine). Each block owns 64 consecutive M
// elements; each of the 4 waves sums 16 of the 64 partials with fully-coalesced
// 256B loads; LDS combine; first 64 threads convert + scatter-store bf16.
__global__ __launch_bounds__(256) void k2_reduce(const float* __restrict__ part,
                                                 unsigned short* __restrict__ MB) {
    __shared__ float red[4][64];
    const int t    = threadIdx.x;
    const int sub  = t >> 6;                 // wave id -> partial group
    const int lane = t & 63;
    const int eg   = blockIdx.x * 64 + lane; // global element 0..16383
    const int b    = eg >> 12;
    const int e    = eg & 4095;
    const float* pp = part + ((size_t)(b * NCH + sub * 16)) * 4096 + e;
    float s = 0.f;
#pragma unroll
    for (int p = 0; p < 16; ++p) s += pp[(size_t)p * 4096];
    red[sub][lane] = s;
    __syncthreads();
    if (t < 64) {
        const float v = red[0][t] + red[1][t] + red[2][t] + red[3][t];
        const int ee  = blockIdx.x * 64 + t;
        const int bb  = ee >> 12;
        const int idx = ee & 4095;
        const int dp = idx >> 6;      // k index (d')
        const int c  = idx & 63;      // n index
        const int ct = c >> 4, mm = c & 15;
        const int ks = dp >> 5, qd = (dp >> 3) & 3, j = dp & 7;
        MB[(((bb * 8 + ct * 2 + ks) * 64) + qd * 16 + mm) * 8 + j] = f2bf(v);
    }
}

// ---------------- k3: out = Q @ M via MFMA, zero LDS ---------------------
// grid 256 (b*64 + rowblock of 64), block 256 = 4 waves x 16 rows each.
__global__ __launch_bounds__(256) void k3_qm(const float* __restrict__ Q,
                                             const unsigned short* __restrict__ MB,
                                             float* __restrict__ out) {
    const int bx = blockIdx.x;
    const int t  = threadIdx.x;
    const int wave = t >> 6, lane = t & 63;
    const int m = lane & 15, quad = lane >> 4;
    const int b = bx >> 6;
    const int row0 = (bx & 63) * 64 + wave * 16;     // row tile within batch

    // A-fragments: Q[row0+m][ks*32 + quad*8 .. +8] -> bf16x8, straight from global
    const float* qrow = Q + ((size_t)b * SEQ + row0 + m) * DIM;
    bf16x8 afrag[2];
#pragma unroll
    for (int ks = 0; ks < 2; ++ks) {
        const f4* qp = (const f4*)(qrow + ks * 32 + quad * 8);
        f4 q1 = qp[0], q2 = qp[1];
        bf16x8 a;
        a[0] = (short)f2bf(q1.x); a[1] = (short)f2bf(q1.y);
        a[2] = (short)f2bf(q1.z); a[3] = (short)f2bf(q1.w);
        a[4] = (short)f2bf(q2.x); a[5] = (short)f2bf(q2.y);
        a[6] = (short)f2bf(q2.z); a[7] = (short)f2bf(q2.w);
        afrag[ks] = a;
    }

    const bf16x8* MBv = (const bf16x8*)MB + (size_t)b * 8 * 64;
    f32x4 acc[4];
#pragma unroll
    for (int ct = 0; ct < 4; ++ct) acc[ct] = (f32x4)0.f;
#pragma unroll
    for (int ct = 0; ct < 4; ++ct) {
#pragma unroll
        for (int ks = 0; ks < 2; ++ks) {
            bf16x8 bfrag = MBv[(ct * 2 + ks) * 64 + lane];
            acc[ct] = __builtin_amdgcn_mfma_f32_16x16x32_bf16(afrag[ks], bfrag, acc[ct], 0, 0, 0);
        }
    }

    // C/D layout: col = ct*16 + (lane&15), row = quad*4 + reg
    float* orow = out + ((size_t)b * SEQ + row0) * DIM;
#pragma unroll
    for (int ct = 0; ct < 4; ++ct) {
#pragma unroll
        for (int r = 0; r < 4; ++r) {
            orow[(quad * 4 + r) * DIM + ct * 16 + m] = acc[ct][r];
        }
    }
}

extern "C" void kernel_launch(void* const* d_in, const int* in_sizes, int n_in,
                              void* d_out, int out_size, void* d_ws, size_t ws_size,
                              hipStream_t stream) {
    const float* q = (const float*)d_in[0];
    const float* k = (const float*)d_in[1];
    const float* v = (const float*)d_in[2];
    float* out = (float*)d_out;

    float* part = (float*)d_ws;                                                      // 4 MiB
    unsigned short* MB = (unsigned short*)((char*)d_ws + (size_t)4 * 1024 * 1024);   // 32 KiB

    k1_partial<<<BATCH * NCH, 256, 0, stream>>>(k, v, part);
    k2_reduce<<<256, 256, 0, stream>>>(part, MB);
    k3_qm<<<BATCH * NCH, 256, 0, stream>>>(q, MB, out);
}